// Round 16
// baseline (29.941 us; speedup 1.0000x reference)
//
#include <hip/hip_runtime.h>

// PixelEffectModule: 8-bin intensity histogram over 11x11 windows at stride 8,
// argmax bin, output that bin's mean RGB, upsampled 8x8.
// Input: rgb (1,3,2048,2048) fp32 in [0,255). Output: (1,3,2048,2048) fp32.
//
// R16 = R14 green (25.2 us, absmax 0.0) + two quantified fixes:
//  1) swz(c) = c ^ ((c>>4)&1): a quarter's 16 lanes read stride-2 chunks
//     (groups {0,2,4,6}, 4-way); parity-flip on bit4 splits them 8 even /
//     8 odd -> 2 lanes/bank-group = ds_read_b128 floor. (R14's swz2 kept
//     parity -> measured 1.58M conflicts.)
//  2) batch 2 vertical cell-rows per WG: their 11-row windows overlap 3
//     rows, so stage 19 rows ONCE (1938 chunks, 16 DMA iters), one drain,
//     compute tile A (staged rows 0..10) then tile B (rows 8..18). Halves
//     drain stalls per tile, -14% staged bytes; tile B runs stall-free.
//  - LDS exactly 32 KB (5 WG/CU): reduce scratch lives in the DMA pad
//    region (chunks 1938..2047, junk-filled during staging, written only
//    after the drain -> no race).
//  - reduce barriers: R13's verified lgkmcnt-only sync (doesn't drain
//    tile A's store vmcnt). Stage drain stays __syncthreads().
//  - math path byte-identical to R14 (bins, packed-u64 counts, nibble
//    cache, argmax, shfl(16/32)+LDS reduces, row writes).

#define Wd 2048
#define HW (2048 * 2048)
#define CPR 34              // 16B chunks per staged row (136 floats)
#define ROWS 19             // staged rows: 2 tiles' windows, 3-row overlap
#define CPC (ROWS * CPR)    // 646 chunks per channel
#define NCHK (3 * CPC)      // 1938 chunks per WG
#define ITERS 16            // 16 x 128 = 2048 chunk slots (110 pad)

typedef unsigned int u32;
typedef unsigned long long u64;
typedef float f32x4 __attribute__((ext_vector_type(4)));

// correctly-rounded t/3 (Markstein), 3 ops vs ~9-inst div expansion
__device__ __forceinline__ float div3(float t) {
    const float c = 0x1.555556p-2f;  // RN(1/3)
    float q0 = t * c;
    float r  = __builtin_fmaf(q0, -3.0f, t);
    return __builtin_fmaf(r, c, q0);
}

// chunk swizzle: parity flip keyed on bit4. Involution; 32,33 fixed points.
__device__ __forceinline__ u32 swz(u32 c) { return c ^ ((c >> 4) & 1u); }

// lgkmcnt-only workgroup sync (R13-verified): does not drain store vmcnt
__device__ __forceinline__ void wgsync_lgkm() {
    asm volatile("s_waitcnt lgkmcnt(0)" ::: "memory");
    __builtin_amdgcn_sched_barrier(0);
    __builtin_amdgcn_s_barrier();
    __builtin_amdgcn_sched_barrier(0);
}

// one tile's compute from staged LDS rows [rowoff, rowoff+10]
__device__ __forceinline__ void compute_tile(const float* __restrict__ ldsf,
                                             float* __restrict__ out,
                                             u64* scp, float4* ssp,
                                             int w, int qid, int cl,
                                             int p, int ox, int oy,
                                             int w0, u32 vmask, int rowoff) {
    const int ytop = oy * 8 - 5;
    const int rs = (p < 3) ? 2 * p : (3 + p);  // first window-row of this part
    const int nr = (p < 3) ? 2 : 1;            // rows: 2,2,2,1,1,1,1,1

#define LOADROW(dst, chn, rr)                                                   \
    {                                                                           \
        int rb_ = ((chn) * ROWS + rowoff + (rr)) * CPR;                         \
        *(f32x4*)((dst) + 0)  = *(const f32x4*)&ldsf[(u32)(rb_ + swz(w0+0))*4u];\
        *(f32x4*)((dst) + 4)  = *(const f32x4*)&ldsf[(u32)(rb_ + swz(w0+1))*4u];\
        *(f32x4*)((dst) + 8)  = *(const f32x4*)&ldsf[(u32)(rb_ + swz(w0+2))*4u];\
        *(f32x4*)((dst) + 12) = *(const f32x4*)&ldsf[(u32)(rb_ + swz(w0+3))*4u];\
    }

    // ---- pass 1: bin pixels, packed byte counts + nibble cache ----
    u64 c64 = 0;
    u32 nbl[2], nbh[2];
#pragma unroll
    for (int k = 0; k < 2; ++k) {
        nbl[k] = 0xFFFFFFFFu; nbh[k] = 0xFFFFFFFFu;
        int r = rs + k;
        int y = ytop + r;                      // uniform per quarter
        if (k < nr && y >= 0) {
            float vR[16], vG[16], vB[16];
            LOADROW(vR, 0, r) LOADROW(vG, 1, r) LOADROW(vB, 2, r)
            u32 bl = 0, bh = 0;
#pragma unroll
            for (int j = 0; j < 14; ++j) {
                float m = div3(vR[j] + vG[j] + vB[j]);
                u32 bin = (u32)(m * 0.03125f);     // trunc(mean/32), exact
                u32 valid = (vmask >> j) & 1u;
                c64 += (u64)valid << (bin << 3);
                u32 binv = valid ? bin : 15u;      // 15 matches no bin
                if (j < 8) bl |= binv << (4 * j);
                else       bh |= binv << (4 * (j - 8));
            }
            nbl[k] = bl; nbh[k] = bh;
        }
    }

    // ---- reduce counts: 4 parts within wave, then 2 waves via LDS ----
    c64 += __shfl_xor(c64, 16);
    c64 += __shfl_xor(c64, 32);
    if (qid == 0) scp[w * 16 + cl] = c64;
    wgsync_lgkm();

    u64 tot = scp[cl] + scp[16 + cl];          // bytes <= 121: no carries
    u32 lo = (u32)tot, hi = (u32)(tot >> 32);
    u32 best = 0, bc = lo & 0xFFu;
#pragma unroll
    for (int b = 1; b < 8; ++b) {
        u32 cb = ((b < 4 ? lo : hi) >> ((b & 3) * 8)) & 0xFFu;
        bool t = cb > bc;
        bc   = t ? cb : bc;
        best = t ? (u32)b : best;
    }

    // ---- pass 2: re-read LDS, sum winning bin via nibbles ----
    float sr = 0.f, sg = 0.f, sb = 0.f;
#pragma unroll
    for (int k = 0; k < 2; ++k) {
        int r = rs + k;
        int y = ytop + r;
        if (k < nr && y >= 0) {
            float vR[16], vG[16], vB[16];
            LOADROW(vR, 0, r) LOADROW(vG, 1, r) LOADROW(vB, 2, r)
            u32 bl = nbl[k], bh = nbh[k];
#pragma unroll
            for (int j = 0; j < 14; ++j) {
                u32 bin = ((j < 8) ? (bl >> (4 * j))
                                   : (bh >> (4 * (j - 8)))) & 0xFu;
                float hm = (bin == best) ? 1.0f : 0.0f;
                sr = __builtin_fmaf(hm, vR[j], sr);
                sg = __builtin_fmaf(hm, vG[j], sg);
                sb = __builtin_fmaf(hm, vB[j], sb);
            }
        }
    }
    sr += __shfl_xor(sr, 16);  sr += __shfl_xor(sr, 32);
    sg += __shfl_xor(sg, 16);  sg += __shfl_xor(sg, 32);
    sb += __shfl_xor(sb, 16);  sb += __shfl_xor(sb, 32);

    if (qid == 0) ssp[w * 16 + cl] = make_float4(sr, sg, sb, 0.f);
    wgsync_lgkm();

    float4 s0 = ssp[cl], s1 = ssp[16 + cl];
    float fbc = (float)bc;
    float orv = (s0.x + s1.x) / fbc;
    float ogv = (s0.y + s1.y) / fbc;
    float obv = (s0.z + s1.z) / fbc;

    // ---- write: part p owns row p of the 8x8 block, 2x float4 per channel ----
    size_t base = (size_t)(oy * 8 + p) * Wd + (size_t)(ox * 8);
    float vals[3] = { orv, ogv, obv };
#pragma unroll
    for (int c = 0; c < 3; ++c) {
        float v = vals[c];
        float4 vv = make_float4(v, v, v, v);
        float* o = out + (size_t)c * HW + base;
        ((float4*)o)[0] = vv;
        ((float4*)o)[1] = vv;
    }
#undef LOADROW
}

__global__ __launch_bounds__(128, 4)
void pixel_effect_kernel(const float* __restrict__ rgb, float* __restrict__ out) {
    __shared__ float ldsf[8192];        // 2048 chunks = 32 KB total LDS
    // reduce scratch inside the DMA pad (chunks 1938..2047; junk during
    // staging, written only after the drain barrier)
    float4* ssp = (float4*)&ldsf[7752];         // 32 x float4 (512 B)
    u64*    scp = (u64*)&ldsf[7752 + 128];      // 32 x u64    (256 B)

    const int tid  = threadIdx.x;       // 0..127
    const int lane = tid & 63;
    const int w    = tid >> 6;          // wave 0..1
    const int qid  = (tid >> 4) & 3;    // quarter within wave
    const int cl   = tid & 15;          // cell within 16-strip
    const int p    = w * 4 + qid;       // row-band part 0..7

    // XCD swizzle (grid 2048 = 8*256, bijective): XCD (wgid&7) owns slots
    // [256*xcd, 256*xcd+256) = 16 contiguous row-pairs x 16 strips.
    u32 wgid = blockIdx.x;
    u32 slot = (wgid & 7u) * 256u + (wgid >> 3);
    const int rp = (int)(slot >> 4);    // row-pair 0..127
    const int tx = (int)(slot & 15u);   // x-strip 0..15
    const int ox = tx * 16 + cl;
    const int oyA = 2 * rp;

    const int xstart = tx ? (tx * 128 - 8) : 0;   // staged 136-float span
    const int ytopA  = oyA * 8 - 5;

    // ---- DMA stage: 1938 chunks (19 rows x 3 ch) -> LDS, one drain ----
#pragma unroll
    for (int it = 0; it < ITERS; ++it) {
        u32 cbase = (u32)it * 128u + (u32)(tid & ~63);  // wave-uniform
        u32 c = cbase + (u32)lane;
        c = c < (NCHK - 1) ? c : (NCHK - 1);            // clamp -> junk to pad
        u32 ch  = (c >= 2u * CPC) ? 2u : (c >= (u32)CPC ? 1u : 0u);
        u32 rem = c - ch * (u32)CPC;
        u32 row = rem / CPR;
        u32 wph = rem - row * CPR;                      // physical chunk-in-row
        u32 wlog = swz(wph);                            // logical chunk to fetch
        int y = ytopA + (int)row; y = y < 0 ? 0 : y;    // clamped rows unread
        const float* gsrc = rgb + (size_t)ch * HW + (size_t)y * Wd
                          + (size_t)(xstart + (int)(wlog * 4u));
        float* ldst = &ldsf[cbase * 4u];                // wave-uniform base
        __builtin_amdgcn_global_load_lds(
            (const __attribute__((address_space(1))) void*)gsrc,
            (__attribute__((address_space(3))) void*)ldst, 16, 0, 0);
    }
    __syncthreads();   // single vmcnt drain for BOTH tiles

    const int lx_off = (ox == 0) ? 0 : (8 * ox - 8 - xstart);  // mult of 8
    const int w0     = lx_off >> 2;                            // even chunk idx
    const u32 vmask  = (ox == 0) ? 0x003Fu : 0x3FF8u;

    // tile A: staged rows 0..10; tile B: staged rows 8..18 (windows overlap 3)
    compute_tile(ldsf, out, scp, ssp, w, qid, cl, p, ox, oyA,     w0, vmask, 0);
    compute_tile(ldsf, out, scp, ssp, w, qid, cl, p, ox, oyA + 1, w0, vmask, 8);
}

extern "C" void kernel_launch(void* const* d_in, const int* in_sizes, int n_in,
                              void* d_out, int out_size, void* d_ws, size_t ws_size,
                              hipStream_t stream) {
    const float* rgb = (const float*)d_in[0];
    float* out = (float*)d_out;
    dim3 block(128, 1, 1);                // 2 waves; wave = 16 cells x 4 parts
    dim3 grid(2048, 1, 1);                // 16 strips x 128 row-pairs (swizzled)
    hipLaunchKernelGGL(pixel_effect_kernel, grid, block, 0, stream, rgb, out);
}